// Round 17
// baseline (87.734 us; speedup 1.0000x reference)
//
#include <hip/hip_runtime.h>
#include <hip/hip_bf16.h>
#include <math.h>

#define NP 4096      // N
#define DD 128       // D
#define N2 8192      // 2N
#define TINV 10.0f   // 1/temperature
#define SHIFT 10.0f  // fixed lse shift (sim <= 10)
#define C1 14.4269504f       // TINV * log2(e): e = 2^(C1*(acc-1))
#define NGL2 -0.0288539004f  // -GAMMA1 * log2(e), GAMMA1 = 0.02

// Mapped constraint frontier (r6-r16): epilogue+acc needs ~92-100 unified regs ->
// only 4 waves/SIMD fits (128-reg budget); tighter bounds spill catastrophically.
// Device-scope atomic partials (r2, r15) serialize at the coherent point: 3x cost.
// Stable: (512,4), VGPR~60-80, 2 blocks/CU, 3 launches, plain stores only.
typedef __attribute__((ext_vector_type(8))) short bf16x8;
typedef __attribute__((ext_vector_type(4))) float f32x4;
typedef __attribute__((ext_vector_type(4))) int i32x4;

__device__ __forceinline__ float bf2f(short s) {
  return __uint_as_float(((unsigned)(unsigned short)s) << 16);
}

// direct global->LDS copy, 16B per lane; lptr must be wave-uniform (HW adds lane*16)
#define GLDS(g, l)                                                                   \
  __builtin_amdgcn_global_load_lds((__attribute__((address_space(1))) const void*)(g), \
                                   (__attribute__((address_space(3))) void*)(l), 16, 0, 0)

// sum over each 16-lane DPP row; result lands in lanes with (lane&15)==0
__device__ __forceinline__ float dpp_red16(float x) {
  x += __int_as_float(__builtin_amdgcn_update_dpp(0, __float_as_int(x), 0x101, 0xF, 0xF, true));
  x += __int_as_float(__builtin_amdgcn_update_dpp(0, __float_as_int(x), 0x102, 0xF, 0xF, true));
  x += __int_as_float(__builtin_amdgcn_update_dpp(0, __float_as_int(x), 0x104, 0xF, 0xF, true));
  x += __int_as_float(__builtin_amdgcn_update_dpp(0, __float_as_int(x), 0x108, 0xF, 0xF, true));
  return x;
}

// ---------------- prep: knorm (blocks 0..2047) || klabel (blocks 2048..6143) ----------------
__global__ __launch_bounds__(256) void kprep(const float* __restrict__ zi,
                                             const float* __restrict__ zj,
                                             const float* __restrict__ labels,
                                             __hip_bfloat16* __restrict__ Z,
                                             float4* __restrict__ rowinfo,
                                             double* __restrict__ accd,
                                             unsigned int* __restrict__ cnt,
                                             float* __restrict__ zsc) {
  int w = threadIdx.x >> 6, lane = threadIdx.x & 63;
  if (blockIdx.x < 2048) {
    // ---- normalize rows -> bf16 ----
    int a = blockIdx.x * 4 + w;
    const float* src = (a < NP) ? (zi + (size_t)a * DD) : (zj + (size_t)(a - NP) * DD);
    float2 v = *(const float2*)(src + lane * 2);
    float ss = v.x * v.x + v.y * v.y;
#pragma unroll
    for (int m = 1; m < 64; m <<= 1) ss += __shfl_xor(ss, m);
    float rn = rsqrtf(ss);
    __hip_bfloat162 o;
    o.x = __float2bfloat16(v.x * rn);
    o.y = __float2bfloat16(v.y * rn);
    *(__hip_bfloat162*)(Z + (size_t)a * DD + lane * 2) = o;
  } else {
    // ---- label row sums ----
    int a = blockIdx.x - 2048;  // 0..NP-1
    if (a == 0) {
      if (threadIdx.x == 0) { *accd = 0.0; cnt[0] = 0u; }
      for (int q = threadIdx.x; q < 384; q += 256) zsc[q] = 0.f;
    }
    float ca = labels[a * 2 + 0], ga = labels[a * 2 + 1];
    float s1 = 0.f, c2 = 0.f;
    for (int m = threadIdx.x; m < NP; m += 256) {
      float2 lm = *(const float2*)(labels + m * 2);
      float dy = ca - lm.x;
      s1 += __builtin_amdgcn_exp2f(dy * dy * NGL2);
      c2 += (ga == lm.y) ? 1.f : 0.f;
    }
#pragma unroll
    for (int m = 1; m < 64; m <<= 1) {
      s1 += __shfl_xor(s1, m);
      c2 += __shfl_xor(c2, m);
    }
    __shared__ float sh[8];
    if (lane == 0) { sh[w] = s1; sh[4 + w] = c2; }
    __syncthreads();
    if (threadIdx.x == 0) {
      s1 = sh[0] + sh[1] + sh[2] + sh[3];
      c2 = sh[4] + sh[5] + sh[6] + sh[7];
      float rs1 = 2.f * s1 - 1.f;         // cont row sum over 8192, diag removed
      float rs2 = (float)NP + c2 - 1.f;   // cat row sum = 4095 + class count
      float4 ri = make_float4(ca, TINV / rs1, ga, TINV / rs2);
      rowinfo[a] = ri;
      rowinfo[a + NP] = ri;
    }
  }
}

// ---------------- main: 512 persistent blocks; per-block tile walk with next-tile prefetch ----------------
// Each XCD chunk = 268 ids (2080 tiles + 64 riders; riders always last in a block's walk).
// Pipeline per tile: MFMA -> bar -> prefetch(next) -> epilogue (hides stage latency) -> bar -> combine.
__global__ __launch_bounds__(512, 4) void kmain(const __hip_bfloat16* __restrict__ Zp,
                                                const float4* __restrict__ rowinfo,
                                                const float* __restrict__ labels,
                                                float2* __restrict__ part,
                                                float* __restrict__ zsc) {
  __shared__ char lds[2 * 128 * 256 + 4 * 512 * 4];  // A panel + B panel + lacc planes
  char* ldsA = lds;
  char* ldsB = lds + 128 * 256;
  float* lacc = (float*)(lds + 2 * 128 * 256);  // [4 planes][512]

  const int t = threadIdx.x;
  const int lane = t & 63, w = t >> 6;
  const int wr = w >> 2, wc = w & 3;     // 2 x 4 wave grid
  const int lrow = lane & 15, lgrp = lane >> 4;
  const char* gZ = (const char*)Zp;      // [8192][256B]

  const int x = blockIdx.x & 7, l = blockIdx.x >> 3;  // XCD chunk, local block
  const int idbase = x * 268, idend = idbase + 268;

  auto decode = [](int tb, int& I, int& J) {
    int i0 = (int)((129.0f - sqrtf(16641.0f - 8.0f * (float)tb)) * 0.5f);
    while (i0 * (129 - i0) / 2 > tb) --i0;
    while ((i0 + 1) * (128 - i0) / 2 <= tb) ++i0;
    I = i0;
    J = i0 + (tb - i0 * (129 - i0) / 2);
  };
  auto stage = [&](int row0, int col0, bool diag) {
#pragma unroll
    for (int i = 0; i < 4; ++i) {
      int chunk = t + i * 512;        // 0..2047 16B chunks
      int r = chunk >> 4;             // 0..127
      int bc = (chunk & 15) << 4;     // linear LDS byte col
      int srcc = bc ^ ((r & 7) << 4); // inverse-swizzled global col
      int uoff = ((t & ~63) + i * 512) * 16;  // wave-uniform LDS byte base
      GLDS(gZ + (size_t)(row0 + r) * 256 + srcc, ldsA + uoff);
    }
    if (!diag) {
#pragma unroll
      for (int i = 0; i < 4; ++i) {
        int chunk = t + i * 512;
        int r = chunk >> 4;
        int bc = (chunk & 15) << 4;
        int srcc = bc ^ ((r & 7) << 4);
        int uoff = ((t & ~63) + i * 512) * 16;
        GLDS(gZ + (size_t)(col0 + r) * 256 + srcc, ldsB + uoff);
      }
    }
  };

  // prologue: stage the first tile
  int curI = 0, curJ = 0;
  {
    int id0 = idbase + l;
    if (id0 < 2080) {
      decode(id0, curI, curJ);
      stage(curI * 128, curJ * 128, curI == curJ);
    }
  }
  __syncthreads();  // panels staged (drains vmcnt)

  for (int k = 0; ; ++k) {
    int id = idbase + l + 64 * k;
    if (id >= idend) break;

    if (id >= 2080) {
      // ---- zsum rider (always last in walk; no prefetch pending) ----
      __syncthreads();
      int b = id - 2080;  // 0..63
      int c = t & 127, rgrp = t >> 7;
      int r0 = b * 128 + rgrp * 32;
      float s0 = 0.f, s1 = 0.f, s2 = 0.f;
      for (int kk = 0; kk < 32; ++kk) {
        int r = r0 + kk;
        float zf = bf2f(((const short*)Zp)[(size_t)r * DD + c]);
        float g = labels[(r & (NP - 1)) * 2 + 1];  // wave-uniform -> scalar load
        s0 += (g == 0.f) ? zf : 0.f;
        s1 += (g == 1.f) ? zf : 0.f;
        s2 += (g == 2.f) ? zf : 0.f;
      }
      float* sh = (float*)lds;  // [4][3][128] (panel region; tile reads long done)
      sh[(rgrp * 3 + 0) * 128 + c] = s0;
      sh[(rgrp * 3 + 1) * 128 + c] = s1;
      sh[(rgrp * 3 + 2) * 128 + c] = s2;
      __syncthreads();
      if (t < 384) {
        int cls = t >> 7, cc = t & 127;
        float v = sh[(0 * 3 + cls) * 128 + cc] + sh[(1 * 3 + cls) * 128 + cc] +
                  sh[(2 * 3 + cls) * 128 + cc] + sh[(3 * 3 + cls) * 128 + cc];
        atomicAdd(&zsc[cls * 128 + cc], v);
      }
      continue;
    }

    const int row0 = curI * 128, col0 = curJ * 128;
    const bool diag = (curI == curJ);
    const char* ldsBp = diag ? ldsA : ldsB;

    // ---- MFMA phase (panels ready from previous prefetch/prologue) ----
    f32x4 acc[4][2] = {};
#pragma unroll
    for (int kk = 0; kk < 4; ++kk) {  // K = 128 in 4 steps of 32
      int bcol = kk * 64 + (lgrp << 4);
      bf16x8 af[4], bfv[2];
#pragma unroll
      for (int mi = 0; mi < 4; ++mi) {
        int r = wr * 64 + mi * 16 + lrow;
        af[mi] = *(const bf16x8*)(ldsA + r * 256 + (bcol ^ ((r & 7) << 4)));
      }
#pragma unroll
      for (int ni = 0; ni < 2; ++ni) {
        int r = wc * 32 + ni * 16 + lrow;
        bfv[ni] = *(const bf16x8*)(ldsBp + r * 256 + (bcol ^ ((r & 7) << 4)));
      }
#pragma unroll
      for (int mi = 0; mi < 4; ++mi)
#pragma unroll
        for (int ni = 0; ni < 2; ++ni)
          acc[mi][ni] = __builtin_amdgcn_mfma_f32_16x16x32_bf16(af[mi], bfv[ni], acc[mi][ni], 0, 0, 0);
    }

    __syncthreads();  // all panel reads done -> panels reusable

    // ---- prefetch next tile (async GLDS; latency hidden under epilogue) ----
    int idn = id + 64;
    int nI = curI, nJ = curJ;
    if (idn < idend && idn < 2080) {
      decode(idn, nI, nJ);
      stage(nI * 128, nJ * 128, nI == nJ);
    }

    // ---- epilogue: plain writes into this wave's planes ----
    float2 rbv[2];  // (y1, TINV/rs1) of col b
#pragma unroll
    for (int ni = 0; ni < 2; ++ni)
      rbv[ni] = *(const float2*)&rowinfo[col0 + wc * 32 + ni * 16 + lrow];

    if (!diag) {
      float ec[2] = {0.f, 0.f}, pc[2] = {0.f, 0.f};
#pragma unroll
      for (int mi = 0; mi < 4; ++mi) {
        int a0 = row0 + wr * 64 + mi * 16 + lgrp * 4;
#pragma unroll
        for (int j = 0; j < 4; ++j) {
          float2 ri = *(const float2*)&rowinfo[a0 + j];
          float es = 0.f, pa = 0.f;
#pragma unroll
          for (int ni = 0; ni < 2; ++ni) {
            float v = acc[mi][ni][j];
            float e = __builtin_amdgcn_exp2f(fmaf(v, C1, -C1));  // exp(sim-10)
            float dy = ri.x - rbv[ni].x;
            float wu = __builtin_amdgcn_exp2f(dy * dy * NGL2);   // cont rbf
            es += e;
            ec[ni] += e;
            pa = fmaf(wu, v, pa);
            pc[ni] = fmaf(wu, v, pc[ni]);
          }
          es = dpp_red16(es);
          float wsum = dpp_red16(pa * ri.y);
          if (lrow == 0) {
            int idx = wr * 64 + mi * 16 + lgrp * 4 + j;  // 0..127
            lacc[wc * 512 + 2 * idx] = es;
            lacc[wc * 512 + 2 * idx + 1] = wsum;
          }
        }
      }
#pragma unroll
      for (int ni = 0; ni < 2; ++ni) {
        float wcol = pc[ni] * rbv[ni].y;
        float e2 = ec[ni] + __shfl_xor(ec[ni], 16);
        e2 += __shfl_xor(e2, 32);
        float w2 = wcol + __shfl_xor(wcol, 16);
        w2 += __shfl_xor(w2, 32);
        if (lane < 16) {
          int idx = 128 + wc * 32 + ni * 16 + lane;  // 128..255
          lacc[wr * 512 + 2 * idx] = e2;
          lacc[wr * 512 + 2 * idx + 1] = w2;
        }
      }
    } else {
#pragma unroll
      for (int mi = 0; mi < 4; ++mi) {
        int a0 = row0 + wr * 64 + mi * 16 + lgrp * 4;
#pragma unroll
        for (int j = 0; j < 4; ++j) {
          int a = a0 + j;
          float2 ri = *(const float2*)&rowinfo[a0 + j];
          float es = 0.f, pa = 0.f;
#pragma unroll
          for (int ni = 0; ni < 2; ++ni) {
            float v = acc[mi][ni][j];
            float nd = (a != col0 + wc * 32 + ni * 16 + lrow) ? 1.f : 0.f;  // kill diagonal
            float e = __builtin_amdgcn_exp2f(fmaf(v, C1, -C1)) * nd;
            float dy = ri.x - rbv[ni].x;
            float wu = __builtin_amdgcn_exp2f(dy * dy * NGL2) * nd;
            es += e;
            pa = fmaf(wu, v, pa);
          }
          es = dpp_red16(es);
          float wsum = dpp_red16(pa * ri.y);
          if (lrow == 0) {
            int idx = wr * 64 + mi * 16 + lgrp * 4 + j;
            lacc[wc * 512 + 2 * idx] = es;
            lacc[wc * 512 + 2 * idx + 1] = wsum;
          }
        }
      }
      // diag: col planes unused; zero planes 0,1 col halves so combine reads zeros
      if (w < 2 && lane < 32) {
#pragma unroll
        for (int i = 0; i < 8; ++i) lacc[w * 512 + 256 + lane * 8 + i] = 0.f;
      }
    }

    __syncthreads();  // planes ready; also drains prefetch vmcnt (hidden by epilogue)

    if (t < 256) {
      float2 p0 = ((float2*)lacc)[t];
      float2 p1 = ((float2*)lacc)[256 + t];
      float2 o;
      if (t < 128) {  // row side: sum planes 0..3
        float2 p2 = ((float2*)lacc)[512 + t];
        float2 p3 = ((float2*)lacc)[768 + t];
        o.x = (p0.x + p1.x) + (p2.x + p3.x);
        o.y = (p0.y + p1.y) + (p2.y + p3.y);
      } else {        // col side: sum planes 0..1
        o.x = p0.x + p1.x;
        o.y = p0.y + p1.y;
      }
      part[(size_t)id * 256 + t] = o;
    }

    curI = nI;
    curJ = nJ;
  }
}

// ---------------- reduce per row-tile (512 thr, 4-way tile-parallel) + cat + log + ticket ----------------
__global__ __launch_bounds__(512) void kreduce(const float2* __restrict__ part,
                                               const __hip_bfloat16* __restrict__ Z,
                                               const float4* __restrict__ rowinfo,
                                               const float* __restrict__ zsc,
                                               double* __restrict__ accd,
                                               unsigned int* __restrict__ cnt,
                                               float* __restrict__ out) {
  int T = blockIdx.x;  // 0..63
  int t = threadIdx.x;
  int r = t & 127, q = t >> 7;  // q in 0..3
  float es = 0.f, ws = 0.f;
  int tb0 = T * (129 - T) / 2;
  for (int k = q; k < 64 - T; k += 4) {  // row-side: tiles (T, J>=T)
    float2 v = part[(size_t)(tb0 + k) * 256 + r];
    es += v.x;
    ws += v.y;
  }
  for (int I = q; I < T; I += 4) {       // col-side: tiles (I<T, T)
    float2 v = part[(size_t)(I * (129 - I) / 2 + T - I) * 256 + 128 + r];
    es += v.x;
    ws += v.y;
  }
  __shared__ float sess[512], swss[512];
  sess[q * 128 + r] = es;
  swss[q * 128 + r] = ws;
  __syncthreads();

  double val = 0.0;
  if (t < 128) {
    es = sess[t] + sess[128 + t] + sess[256 + t] + sess[384 + t];
    ws = swss[t] + swss[128 + t] + swss[256 + t] + swss[384 + t];
    // categorical closed form: cat = (0.5*(d_tot-1) + 0.5*(d_cls-1)) * TINV/rs2
    int a = T * 128 + t;
    float4 ri = rowinfo[a];
    int cls = (int)ri.z;
    const float* zc = zsc + cls * DD;
    float d1 = 0.f, d2 = 0.f;
    const __hip_bfloat16* zrow = Z + (size_t)a * DD;
#pragma unroll
    for (int k = 0; k < 16; ++k) {
      bf16x8 zv = *(const bf16x8*)(zrow + k * 8);
#pragma unroll
      for (int e = 0; e < 8; ++e) {
        int col = k * 8 + e;
        float zf = bf2f(zv[e]);
        float tot = zsc[col] + zsc[128 + col] + zsc[256 + col];
        d1 = fmaf(zf, tot, d1);
        d2 = fmaf(zf, zc[col], d2);
      }
    }
    ws += (0.5f * (d1 - 1.0f) + 0.5f * (d2 - 1.0f)) * ri.w;  // ri.w = TINV/rs2
    val = (double)ws - 2.0 * (double)(SHIFT + __logf(es));
  }
#pragma unroll
  for (int m = 1; m < 64; m <<= 1) val += __shfl_xor(val, m);
  __shared__ double shd[8];
  if ((t & 63) == 0) shd[t >> 6] = val;
  __syncthreads();
  if (t == 0) {
    double bsum = shd[0] + shd[1] + shd[2] + shd[3] + shd[4] + shd[5] + shd[6] + shd[7];
    atomicAdd(accd, bsum);
    __threadfence();
    unsigned int old = atomicAdd(cnt, 1u);
    if (old == 63u) {  // last block finishes
      double tot = atomicAdd(accd, 0.0);  // device-scope coherent read
      out[0] = (float)(-tot / (double)NP);
    }
  }
}

extern "C" void kernel_launch(void* const* d_in, const int* in_sizes, int n_in,
                              void* d_out, int out_size, void* d_ws, size_t ws_size,
                              hipStream_t stream) {
  const float* zi = (const float*)d_in[0];
  const float* zj = (const float*)d_in[1];
  const float* labels = (const float*)d_in[2];
  float* out = (float*)d_out;
  char* ws = (char*)d_ws;

  float4* rowinfo = (float4*)ws;                           // 128 KiB
  double* accd = (double*)(ws + 128 * 1024);               // 8 B
  unsigned int* cnt = (unsigned int*)(ws + 128 * 1024 + 8);
  float* zsc = (float*)(ws + 132 * 1024);                  // 3x128 f32
  __hip_bfloat16* Z = (__hip_bfloat16*)(ws + 256 * 1024);  // 2 MiB
  float2* part = (float2*)(ws + 256 * 1024 + 2 * 1024 * 1024);  // 2080*256*8B = 4.16 MiB

  kprep<<<6144, 256, 0, stream>>>(zi, zj, labels, Z, rowinfo, accd, cnt, zsc);
  kmain<<<512, 512, 0, stream>>>(Z, rowinfo, labels, part, zsc);
  kreduce<<<64, 512, 0, stream>>>(part, Z, rowinfo, zsc, accd, cnt, out);
}

// Round 18
// 59.007 us; speedup vs baseline: 1.4868x; 1.4868x over previous
//
#include <hip/hip_runtime.h>
#include <hip/hip_bf16.h>
#include <math.h>

#define NP 4096      // N
#define DD 128       // D
#define N2 8192      // 2N
#define TINV 10.0f   // 1/temperature
#define SHIFT 10.0f  // fixed lse shift (sim <= 10)
#define C1 14.4269504f       // TINV * log2(e): e = 2^(C1*(acc-1))
#define NGL2 -0.0288539004f  // -GAMMA1 * log2(e), GAMMA1 = 0.02

// Mapped constraint frontier (r6-r17): epilogue+acc needs ~92-100 unified regs ->
// only 4 waves/SIMD fits (128-reg budget); tighter bounds spill catastrophically.
// Device-scope atomic partials (r2, r15) serialize at the coherent point: 3x cost.
// Persistent-block prefetch (r17) destroys L2 tile locality: oversubscribed 2080-block
// grid already provides inter-block overlap for free. Stable optimum: (512,4) x 2144
// blocks, VGPR~64, 2 blocks/CU, 3 launches, plain stores, per-wave-plane epilogue.
typedef __attribute__((ext_vector_type(8))) short bf16x8;
typedef __attribute__((ext_vector_type(4))) float f32x4;
typedef __attribute__((ext_vector_type(4))) int i32x4;

__device__ __forceinline__ float bf2f(short s) {
  return __uint_as_float(((unsigned)(unsigned short)s) << 16);
}

// direct global->LDS copy, 16B per lane; lptr must be wave-uniform (HW adds lane*16)
#define GLDS(g, l)                                                                   \
  __builtin_amdgcn_global_load_lds((__attribute__((address_space(1))) const void*)(g), \
                                   (__attribute__((address_space(3))) void*)(l), 16, 0, 0)

// sum over each 16-lane DPP row; result lands in lanes with (lane&15)==0
__device__ __forceinline__ float dpp_red16(float x) {
  x += __int_as_float(__builtin_amdgcn_update_dpp(0, __float_as_int(x), 0x101, 0xF, 0xF, true));
  x += __int_as_float(__builtin_amdgcn_update_dpp(0, __float_as_int(x), 0x102, 0xF, 0xF, true));
  x += __int_as_float(__builtin_amdgcn_update_dpp(0, __float_as_int(x), 0x104, 0xF, 0xF, true));
  x += __int_as_float(__builtin_amdgcn_update_dpp(0, __float_as_int(x), 0x108, 0xF, 0xF, true));
  return x;
}

// ---------------- prep: knorm (blocks 0..2047) || klabel (blocks 2048..6143) ----------------
__global__ __launch_bounds__(256) void kprep(const float* __restrict__ zi,
                                             const float* __restrict__ zj,
                                             const float* __restrict__ labels,
                                             __hip_bfloat16* __restrict__ Z,
                                             float4* __restrict__ rowinfo,
                                             double* __restrict__ accd,
                                             unsigned int* __restrict__ cnt,
                                             float* __restrict__ zsc) {
  int w = threadIdx.x >> 6, lane = threadIdx.x & 63;
  if (blockIdx.x < 2048) {
    // ---- normalize rows -> bf16 ----
    int a = blockIdx.x * 4 + w;
    const float* src = (a < NP) ? (zi + (size_t)a * DD) : (zj + (size_t)(a - NP) * DD);
    float2 v = *(const float2*)(src + lane * 2);
    float ss = v.x * v.x + v.y * v.y;
#pragma unroll
    for (int m = 1; m < 64; m <<= 1) ss += __shfl_xor(ss, m);
    float rn = rsqrtf(ss);
    __hip_bfloat162 o;
    o.x = __float2bfloat16(v.x * rn);
    o.y = __float2bfloat16(v.y * rn);
    *(__hip_bfloat162*)(Z + (size_t)a * DD + lane * 2) = o;
  } else {
    // ---- label row sums ----
    int a = blockIdx.x - 2048;  // 0..NP-1
    if (a == 0) {
      if (threadIdx.x == 0) { *accd = 0.0; cnt[0] = 0u; }
      for (int q = threadIdx.x; q < 384; q += 256) zsc[q] = 0.f;
    }
    float ca = labels[a * 2 + 0], ga = labels[a * 2 + 1];
    float s1 = 0.f, c2 = 0.f;
    for (int m = threadIdx.x; m < NP; m += 256) {
      float2 lm = *(const float2*)(labels + m * 2);
      float dy = ca - lm.x;
      s1 += __builtin_amdgcn_exp2f(dy * dy * NGL2);
      c2 += (ga == lm.y) ? 1.f : 0.f;
    }
#pragma unroll
    for (int m = 1; m < 64; m <<= 1) {
      s1 += __shfl_xor(s1, m);
      c2 += __shfl_xor(c2, m);
    }
    __shared__ float sh[8];
    if (lane == 0) { sh[w] = s1; sh[4 + w] = c2; }
    __syncthreads();
    if (threadIdx.x == 0) {
      s1 = sh[0] + sh[1] + sh[2] + sh[3];
      c2 = sh[4] + sh[5] + sh[6] + sh[7];
      float rs1 = 2.f * s1 - 1.f;         // cont row sum over 8192, diag removed
      float rs2 = (float)NP + c2 - 1.f;   // cat row sum = 4095 + class count
      float4 ri = make_float4(ca, TINV / rs1, ga, TINV / rs2);
      rowinfo[a] = ri;
      rowinfo[a + NP] = ri;
    }
  }
}

// ---------------- main: 2080 tile blocks (512 thr) + 64 riders; per-wave-plane epilogue ----------------
// LDS: 64 KiB panels + 8 KiB lacc[4][512] (non-aliased -> no repurpose barrier, no atomics).
// part[tb] = float2[256]: [0..127] row-side (es, ws_cont), [128..255] col-side.
__global__ __launch_bounds__(512, 4) void kmain(const __hip_bfloat16* __restrict__ Zp,
                                                const float4* __restrict__ rowinfo,
                                                const float* __restrict__ labels,
                                                float2* __restrict__ part,
                                                float* __restrict__ zsc) {
  __shared__ char lds[2 * 128 * 256 + 4 * 512 * 4];  // A panel + B panel + lacc planes

  // bijective XCD swizzle (2144 % 8 == 0): each XCD gets 268 consecutive ids
  int id = (blockIdx.x & 7) * 268 + (blockIdx.x >> 3);
  const int t = threadIdx.x;
  const int lane = t & 63, w = t >> 6;

  if (id >= 2080) {
    // ---- zsum rider: 128-row stripe, coalesced; per-class column sums ----
    int b = id - 2080;  // 0..63
    int c = t & 127, rgrp = t >> 7;
    int r0 = b * 128 + rgrp * 32;
    float s0 = 0.f, s1 = 0.f, s2 = 0.f;
    for (int k = 0; k < 32; ++k) {
      int r = r0 + k;
      float zf = bf2f(((const short*)Zp)[(size_t)r * DD + c]);
      float g = labels[(r & (NP - 1)) * 2 + 1];  // wave-uniform -> scalar load
      s0 += (g == 0.f) ? zf : 0.f;
      s1 += (g == 1.f) ? zf : 0.f;
      s2 += (g == 2.f) ? zf : 0.f;
    }
    float* sh = (float*)lds;  // [4][3][128]
    sh[(rgrp * 3 + 0) * 128 + c] = s0;
    sh[(rgrp * 3 + 1) * 128 + c] = s1;
    sh[(rgrp * 3 + 2) * 128 + c] = s2;
    __syncthreads();
    if (t < 384) {
      int cls = t >> 7, cc = t & 127;
      float v = sh[(0 * 3 + cls) * 128 + cc] + sh[(1 * 3 + cls) * 128 + cc] +
                sh[(2 * 3 + cls) * 128 + cc] + sh[(3 * 3 + cls) * 128 + cc];
      atomicAdd(&zsc[cls * 128 + cc], v);
    }
    return;
  }

  // ---- tile block: 8 waves (2x4), each owns a 64x32 sub-tile ----
  char* ldsA = lds;
  char* ldsB = lds + 128 * 256;
  float* lacc = (float*)(lds + 2 * 128 * 256);  // [4 planes][512]
  int tb = id;
  // triangular decode: largest I with I*(129-I)/2 <= tb
  int I = (int)((129.0f - sqrtf(16641.0f - 8.0f * (float)tb)) * 0.5f);
  while (I * (129 - I) / 2 > tb) --I;
  while ((I + 1) * (128 - I) / 2 <= tb) ++I;
  int J = I + (tb - I * (129 - I) / 2);
  const bool diag = (I == J);
  const int row0 = I * 128, col0 = J * 128;
  const char* gZ = (const char*)Zp;  // [8192][256B]
  const char* ldsBp = diag ? ldsA : ldsB;

  const int wr = w >> 2, wc = w & 3;     // 2 x 4 wave grid
  const int lrow = lane & 15, lgrp = lane >> 4;

  // ---- stage full-K panels via direct global->LDS (linear dest, pre-swizzled source) ----
#pragma unroll
  for (int i = 0; i < 4; ++i) {
    int chunk = t + i * 512;        // 0..2047 16B chunks
    int r = chunk >> 4;             // 0..127
    int bc = (chunk & 15) << 4;     // linear LDS byte col 0..240
    int srcc = bc ^ ((r & 7) << 4); // inverse-swizzled global col
    int uoff = ((t & ~63) + i * 512) * 16;  // wave-uniform LDS byte base
    GLDS(gZ + (size_t)(row0 + r) * 256 + srcc, ldsA + uoff);
  }
  if (!diag) {
#pragma unroll
    for (int i = 0; i < 4; ++i) {
      int chunk = t + i * 512;
      int r = chunk >> 4;
      int bc = (chunk & 15) << 4;
      int srcc = bc ^ ((r & 7) << 4);
      int uoff = ((t & ~63) + i * 512) * 16;
      GLDS(gZ + (size_t)(col0 + r) * 256 + srcc, ldsB + uoff);
    }
  }
  __syncthreads();  // drains vmcnt for global_load_lds

  f32x4 acc[4][2] = {};
#pragma unroll
  for (int kk = 0; kk < 4; ++kk) {  // K = 128 in 4 steps of 32
    int bcol = kk * 64 + (lgrp << 4);
    bf16x8 af[4], bfv[2];
#pragma unroll
    for (int mi = 0; mi < 4; ++mi) {
      int r = wr * 64 + mi * 16 + lrow;
      af[mi] = *(const bf16x8*)(ldsA + r * 256 + (bcol ^ ((r & 7) << 4)));
    }
#pragma unroll
    for (int ni = 0; ni < 2; ++ni) {
      int r = wc * 32 + ni * 16 + lrow;
      bfv[ni] = *(const bf16x8*)(ldsBp + r * 256 + (bcol ^ ((r & 7) << 4)));
    }
#pragma unroll
    for (int mi = 0; mi < 4; ++mi)
#pragma unroll
      for (int ni = 0; ni < 2; ++ni)
        acc[mi][ni] = __builtin_amdgcn_mfma_f32_16x16x32_bf16(af[mi], bfv[ni], acc[mi][ni], 0, 0, 0);
  }

  // ---- epilogue: plain writes into this wave's planes (rows -> plane wc, cols -> plane wr) ----
  float2 rbv[2];  // (y1, TINV/rs1) of col b
#pragma unroll
  for (int ni = 0; ni < 2; ++ni)
    rbv[ni] = *(const float2*)&rowinfo[col0 + wc * 32 + ni * 16 + lrow];

  if (!diag) {
    float ec[2] = {0.f, 0.f}, pc[2] = {0.f, 0.f};
#pragma unroll
    for (int mi = 0; mi < 4; ++mi) {
      int a0 = row0 + wr * 64 + mi * 16 + lgrp * 4;
#pragma unroll
      for (int j = 0; j < 4; ++j) {
        float2 ri = *(const float2*)&rowinfo[a0 + j];
        float es = 0.f, pa = 0.f;
#pragma unroll
        for (int ni = 0; ni < 2; ++ni) {
          float v = acc[mi][ni][j];
          float e = __builtin_amdgcn_exp2f(fmaf(v, C1, -C1));  // exp(sim-10)
          float dy = ri.x - rbv[ni].x;
          float wu = __builtin_amdgcn_exp2f(dy * dy * NGL2);   // cont rbf
          es += e;
          ec[ni] += e;
          pa = fmaf(wu, v, pa);
          pc[ni] = fmaf(wu, v, pc[ni]);
        }
        es = dpp_red16(es);
        float wsum = dpp_red16(pa * ri.y);
        if (lrow == 0) {
          int idx = wr * 64 + mi * 16 + lgrp * 4 + j;  // 0..127
          lacc[wc * 512 + 2 * idx] = es;
          lacc[wc * 512 + 2 * idx + 1] = wsum;
        }
      }
    }
#pragma unroll
    for (int ni = 0; ni < 2; ++ni) {
      float wcol = pc[ni] * rbv[ni].y;
      float e2 = ec[ni] + __shfl_xor(ec[ni], 16);
      e2 += __shfl_xor(e2, 32);
      float w2 = wcol + __shfl_xor(wcol, 16);
      w2 += __shfl_xor(w2, 32);
      if (lane < 16) {
        int idx = 128 + wc * 32 + ni * 16 + lane;  // 128..255
        lacc[wr * 512 + 2 * idx] = e2;
        lacc[wr * 512 + 2 * idx + 1] = w2;
      }
    }
  } else {
#pragma unroll
    for (int mi = 0; mi < 4; ++mi) {
      int a0 = row0 + wr * 64 + mi * 16 + lgrp * 4;
#pragma unroll
      for (int j = 0; j < 4; ++j) {
        int a = a0 + j;
        float2 ri = *(const float2*)&rowinfo[a0 + j];
        float es = 0.f, pa = 0.f;
#pragma unroll
        for (int ni = 0; ni < 2; ++ni) {
          float v = acc[mi][ni][j];
          float nd = (a != col0 + wc * 32 + ni * 16 + lrow) ? 1.f : 0.f;  // kill diagonal
          float e = __builtin_amdgcn_exp2f(fmaf(v, C1, -C1)) * nd;
          float dy = ri.x - rbv[ni].x;
          float wu = __builtin_amdgcn_exp2f(dy * dy * NGL2) * nd;
          es += e;
          pa = fmaf(wu, v, pa);
        }
        es = dpp_red16(es);
        float wsum = dpp_red16(pa * ri.y);
        if (lrow == 0) {
          int idx = wr * 64 + mi * 16 + lgrp * 4 + j;
          lacc[wc * 512 + 2 * idx] = es;
          lacc[wc * 512 + 2 * idx + 1] = wsum;
        }
      }
    }
    // diag: col planes unused; zero planes 0,1 col region so the sum reads zeros
    if (w < 2 && lane < 32) {
#pragma unroll
      for (int i = 0; i < 8; ++i) lacc[w * 512 + 256 + lane * 8 + i] = 0.f;
    }
  }

  __syncthreads();
  if (t < 256) {
    float2 p0 = ((float2*)lacc)[t];
    float2 p1 = ((float2*)lacc)[256 + t];
    float2 o;
    if (t < 128) {  // row side: sum planes 0..3
      float2 p2 = ((float2*)lacc)[512 + t];
      float2 p3 = ((float2*)lacc)[768 + t];
      o.x = (p0.x + p1.x) + (p2.x + p3.x);
      o.y = (p0.y + p1.y) + (p2.y + p3.y);
    } else {        // col side: sum planes 0..1
      o.x = p0.x + p1.x;
      o.y = p0.y + p1.y;
    }
    part[(size_t)tb * 256 + t] = o;
  }
}

// ---------------- reduce per row-tile (512 thr, 4-way tile-parallel) + cat + log + ticket ----------------
__global__ __launch_bounds__(512) void kreduce(const float2* __restrict__ part,
                                               const __hip_bfloat16* __restrict__ Z,
                                               const float4* __restrict__ rowinfo,
                                               const float* __restrict__ zsc,
                                               double* __restrict__ accd,
                                               unsigned int* __restrict__ cnt,
                                               float* __restrict__ out) {
  int T = blockIdx.x;  // 0..63
  int t = threadIdx.x;
  int r = t & 127, q = t >> 7;  // q in 0..3
  float es = 0.f, ws = 0.f;
  int tb0 = T * (129 - T) / 2;
  for (int k = q; k < 64 - T; k += 4) {  // row-side: tiles (T, J>=T)
    float2 v = part[(size_t)(tb0 + k) * 256 + r];
    es += v.x;
    ws += v.y;
  }
  for (int I = q; I < T; I += 4) {       // col-side: tiles (I<T, T)
    float2 v = part[(size_t)(I * (129 - I) / 2 + T - I) * 256 + 128 + r];
    es += v.x;
    ws += v.y;
  }
  __shared__ float sess[512], swss[512];
  sess[q * 128 + r] = es;
  swss[q * 128 + r] = ws;
  __syncthreads();

  double val = 0.0;
  if (t < 128) {
    es = sess[t] + sess[128 + t] + sess[256 + t] + sess[384 + t];
    ws = swss[t] + swss[128 + t] + swss[256 + t] + swss[384 + t];
    // categorical closed form: cat = (0.5*(d_tot-1) + 0.5*(d_cls-1)) * TINV/rs2
    int a = T * 128 + t;
    float4 ri = rowinfo[a];
    int cls = (int)ri.z;
    const float* zc = zsc + cls * DD;
    float d1 = 0.f, d2 = 0.f;
    const __hip_bfloat16* zrow = Z + (size_t)a * DD;
#pragma unroll
    for (int k = 0; k < 16; ++k) {
      bf16x8 zv = *(const bf16x8*)(zrow + k * 8);
#pragma unroll
      for (int e = 0; e < 8; ++e) {
        int col = k * 8 + e;
        float zf = bf2f(zv[e]);
        float tot = zsc[col] + zsc[128 + col] + zsc[256 + col];
        d1 = fmaf(zf, tot, d1);
        d2 = fmaf(zf, zc[col], d2);
      }
    }
    ws += (0.5f * (d1 - 1.0f) + 0.5f * (d2 - 1.0f)) * ri.w;  // ri.w = TINV/rs2
    val = (double)ws - 2.0 * (double)(SHIFT + __logf(es));
  }
#pragma unroll
  for (int m = 1; m < 64; m <<= 1) val += __shfl_xor(val, m);
  __shared__ double shd[8];
  if ((t & 63) == 0) shd[t >> 6] = val;
  __syncthreads();
  if (t == 0) {
    double bsum = shd[0] + shd[1] + shd[2] + shd[3] + shd[4] + shd[5] + shd[6] + shd[7];
    atomicAdd(accd, bsum);
    __threadfence();
    unsigned int old = atomicAdd(cnt, 1u);
    if (old == 63u) {  // last block finishes
      double tot = atomicAdd(accd, 0.0);  // device-scope coherent read
      out[0] = (float)(-tot / (double)NP);
    }
  }
}

extern "C" void kernel_launch(void* const* d_in, const int* in_sizes, int n_in,
                              void* d_out, int out_size, void* d_ws, size_t ws_size,
                              hipStream_t stream) {
  const float* zi = (const float*)d_in[0];
  const float* zj = (const float*)d_in[1];
  const float* labels = (const float*)d_in[2];
  float* out = (float*)d_out;
  char* ws = (char*)d_ws;

  float4* rowinfo = (float4*)ws;                           // 128 KiB
  double* accd = (double*)(ws + 128 * 1024);               // 8 B
  unsigned int* cnt = (unsigned int*)(ws + 128 * 1024 + 8);
  float* zsc = (float*)(ws + 132 * 1024);                  // 3x128 f32
  __hip_bfloat16* Z = (__hip_bfloat16*)(ws + 256 * 1024);  // 2 MiB
  float2* part = (float2*)(ws + 256 * 1024 + 2 * 1024 * 1024);  // 2080*256*8B = 4.16 MiB

  kprep<<<6144, 256, 0, stream>>>(zi, zj, labels, Z, rowinfo, accd, cnt, zsc);
  kmain<<<2144, 512, 0, stream>>>(Z, rowinfo, labels, part, zsc);
  kreduce<<<64, 512, 0, stream>>>(part, Z, rowinfo, zsc, accd, cnt, out);
}